// Round 1
// baseline (171.204 us; speedup 1.0000x reference)
//
#include <hip/hip_runtime.h>

#define D_CLAMP 10.0f
#define EPS_F   1e-4f
#define Z_F     10.0f

// One block per (b, i) frame. 256 threads stride over j atoms.
__global__ __launch_bounds__(256) void fape_kernel(
    const float* __restrict__ pred_rot,   // [B,N,3,3]
    const float* __restrict__ pred_trans, // [B,N,3]
    const float* __restrict__ pred_pos,   // [B,N,3]
    const float* __restrict__ true_rot,   // [B,N,3,3]
    const float* __restrict__ true_trans, // [B,N,3]
    const float* __restrict__ true_pos,   // [B,N,3]
    float* __restrict__ out,              // [B]
    int N)
{
    const int bi = blockIdx.x;        // b*N + i
    const int b  = bi / N;

    // Broadcast-load this frame's rotations (all lanes same address -> cache broadcast).
    const float* Rp = pred_rot + (size_t)bi * 9;
    const float* Rt = true_rot + (size_t)bi * 9;
    float rp[9], rt[9];
#pragma unroll
    for (int k = 0; k < 9; ++k) { rp[k] = Rp[k]; rt[k] = Rt[k]; }

    const float* tpv = pred_trans + (size_t)bi * 3;
    const float* ttv = true_trans + (size_t)bi * 3;
    const float tp0 = tpv[0], tp1 = tpv[1], tp2 = tpv[2];
    const float tt0 = ttv[0], tt1 = ttv[1], tt2 = ttv[2];

    // c[o] = (Rp^T tp)[o] - (Rt^T tt)[o];  (R^T v)[o] = sum_p R[p][o] v[p]
    const float c0 = (rp[0]*tp0 + rp[3]*tp1 + rp[6]*tp2) - (rt[0]*tt0 + rt[3]*tt1 + rt[6]*tt2);
    const float c1 = (rp[1]*tp0 + rp[4]*tp1 + rp[7]*tp2) - (rt[1]*tt0 + rt[4]*tt1 + rt[7]*tt2);
    const float c2 = (rp[2]*tp0 + rp[5]*tp1 + rp[8]*tp2) - (rt[2]*tt0 + rt[5]*tt1 + rt[8]*tt2);

    const float* xp = pred_pos + (size_t)b * N * 3;
    const float* xt = true_pos + (size_t)b * N * 3;

    float sum = 0.0f;
    for (int j = threadIdx.x; j < N; j += 256) {
        const float a0 = xp[3*j+0], a1 = xp[3*j+1], a2 = xp[3*j+2];
        const float b0 = xt[3*j+0], b1 = xt[3*j+1], b2 = xt[3*j+2];
        const float d0 = (rp[0]*a0 + rp[3]*a1 + rp[6]*a2) - (rt[0]*b0 + rt[3]*b1 + rt[6]*b2) - c0;
        const float d1 = (rp[1]*a0 + rp[4]*a1 + rp[7]*a2) - (rt[1]*b0 + rt[4]*b1 + rt[7]*b2) - c1;
        const float d2 = (rp[2]*a0 + rp[5]*a1 + rp[8]*a2) - (rt[2]*b0 + rt[5]*b1 + rt[8]*b2) - c2;
        const float dist = sqrtf(d0*d0 + d1*d1 + d2*d2 + EPS_F);
        sum += fminf(dist, D_CLAMP);
    }

    // Wave (64-lane) shuffle reduction.
#pragma unroll
    for (int off = 32; off > 0; off >>= 1)
        sum += __shfl_down(sum, off, 64);

    __shared__ float smem[4];
    const int lane = threadIdx.x & 63;
    const int wave = threadIdx.x >> 6;
    if (lane == 0) smem[wave] = sum;
    __syncthreads();

    if (threadIdx.x == 0) {
        const float s = smem[0] + smem[1] + smem[2] + smem[3];
        const float scale = 1.0f / (Z_F * (float)N * (float)N);
        atomicAdd(out + b, s * scale);
    }
}

extern "C" void kernel_launch(void* const* d_in, const int* in_sizes, int n_in,
                              void* d_out, int out_size, void* d_ws, size_t ws_size,
                              hipStream_t stream) {
    const float* pred_rot   = (const float*)d_in[0];
    const float* pred_trans = (const float*)d_in[1];
    const float* pred_pos   = (const float*)d_in[2];
    const float* true_rot   = (const float*)d_in[3];
    const float* true_trans = (const float*)d_in[4];
    const float* true_pos   = (const float*)d_in[5];
    float* out = (float*)d_out;

    const int B = out_size;                  // 4
    const int BN = in_sizes[1] / 3;          // B*N
    const int N = BN / B;                    // 2048

    hipMemsetAsync(out, 0, (size_t)out_size * sizeof(float), stream);
    fape_kernel<<<BN, 256, 0, stream>>>(pred_rot, pred_trans, pred_pos,
                                        true_rot, true_trans, true_pos,
                                        out, N);
}

// Round 2
// 92.557 us; speedup vs baseline: 1.8497x; 1.8497x over previous
//
#include <hip/hip_runtime.h>

#define D_CLAMP 10.0f
#define EPS_F   1e-4f
#define Z_F     10.0f
#define I_TILE  8

// Each block owns I_TILE consecutive frames (i) of one batch b; frame constants
// live in registers. 256 threads stride over j atoms; each j-load is amortized
// over I_TILE pair computations (compute:load ~36:1 -> latency hidden).
__global__ __launch_bounds__(256) void fape_kernel(
    const float* __restrict__ pred_rot,   // [B,N,3,3]
    const float* __restrict__ pred_trans, // [B,N,3]
    const float* __restrict__ pred_pos,   // [B,N,3]
    const float* __restrict__ true_rot,   // [B,N,3,3]
    const float* __restrict__ true_trans, // [B,N,3]
    const float* __restrict__ true_pos,   // [B,N,3]
    float* __restrict__ out,              // [B]
    int N)
{
    const int tilesPerB = (N + I_TILE - 1) / I_TILE;
    const int b  = blockIdx.x / tilesPerB;
    const int i0 = (blockIdx.x % tilesPerB) * I_TILE;

    // Per-frame constants in registers. rp/rt stored column-major-ish as used:
    // (R^T v)[o] = R[0][o]*v0 + R[1][o]*v1 + R[2][o]*v2  -> need R[p*3+o].
    float rp[I_TILE][9], rt[I_TILE][9], cc[I_TILE][3], w[I_TILE];
#pragma unroll
    for (int k = 0; k < I_TILE; ++k) {
        const int ii = i0 + k;
        const int iv = ii < N ? ii : N - 1;
        w[k] = ii < N ? 1.0f : 0.0f;
        const size_t fi = (size_t)b * N + iv;
        const float* Rp = pred_rot + fi * 9;
        const float* Rt = true_rot + fi * 9;
#pragma unroll
        for (int q = 0; q < 9; ++q) { rp[k][q] = Rp[q]; rt[k][q] = Rt[q]; }
        const float* tpv = pred_trans + fi * 3;
        const float* ttv = true_trans + fi * 3;
        const float tp0 = tpv[0], tp1 = tpv[1], tp2 = tpv[2];
        const float tt0 = ttv[0], tt1 = ttv[1], tt2 = ttv[2];
        cc[k][0] = (rp[k][0]*tp0 + rp[k][3]*tp1 + rp[k][6]*tp2)
                 - (rt[k][0]*tt0 + rt[k][3]*tt1 + rt[k][6]*tt2);
        cc[k][1] = (rp[k][1]*tp0 + rp[k][4]*tp1 + rp[k][7]*tp2)
                 - (rt[k][1]*tt0 + rt[k][4]*tt1 + rt[k][7]*tt2);
        cc[k][2] = (rp[k][2]*tp0 + rp[k][5]*tp1 + rp[k][8]*tp2)
                 - (rt[k][2]*tt0 + rt[k][5]*tt1 + rt[k][8]*tt2);
    }

    const float* xp = pred_pos + (size_t)b * N * 3;
    const float* xt = true_pos + (size_t)b * N * 3;

    float sum = 0.0f;
    for (int j = threadIdx.x; j < N; j += 256) {
        const float a0 = xp[3*j+0], a1 = xp[3*j+1], a2 = xp[3*j+2];
        const float b0 = xt[3*j+0], b1 = xt[3*j+1], b2 = xt[3*j+2];
#pragma unroll
        for (int k = 0; k < I_TILE; ++k) {
            // apart seeded with -c, bpart plain; d = apart - bpart
            const float d0 = fmaf(rp[k][0], a0, fmaf(rp[k][3], a1, fmaf(rp[k][6], a2, -cc[k][0])))
                           - fmaf(rt[k][0], b0, fmaf(rt[k][3], b1, rt[k][6] * b2));
            const float d1 = fmaf(rp[k][1], a0, fmaf(rp[k][4], a1, fmaf(rp[k][7], a2, -cc[k][1])))
                           - fmaf(rt[k][1], b0, fmaf(rt[k][4], b1, rt[k][7] * b2));
            const float d2 = fmaf(rp[k][2], a0, fmaf(rp[k][5], a1, fmaf(rp[k][8], a2, -cc[k][2])))
                           - fmaf(rt[k][2], b0, fmaf(rt[k][5], b1, rt[k][8] * b2));
            const float d2sum = fmaf(d0, d0, fmaf(d1, d1, fmaf(d2, d2, EPS_F)));
            const float dist = __builtin_amdgcn_sqrtf(d2sum);
            sum = fmaf(w[k], fminf(dist, D_CLAMP), sum);
        }
    }

    // Wave (64-lane) shuffle reduction.
#pragma unroll
    for (int off = 32; off > 0; off >>= 1)
        sum += __shfl_down(sum, off, 64);

    __shared__ float smem[4];
    const int lane = threadIdx.x & 63;
    const int wave = threadIdx.x >> 6;
    if (lane == 0) smem[wave] = sum;
    __syncthreads();

    if (threadIdx.x == 0) {
        const float s = smem[0] + smem[1] + smem[2] + smem[3];
        const float scale = 1.0f / (Z_F * (float)N * (float)N);
        atomicAdd(out + b, s * scale);
    }
}

extern "C" void kernel_launch(void* const* d_in, const int* in_sizes, int n_in,
                              void* d_out, int out_size, void* d_ws, size_t ws_size,
                              hipStream_t stream) {
    const float* pred_rot   = (const float*)d_in[0];
    const float* pred_trans = (const float*)d_in[1];
    const float* pred_pos   = (const float*)d_in[2];
    const float* true_rot   = (const float*)d_in[3];
    const float* true_trans = (const float*)d_in[4];
    const float* true_pos   = (const float*)d_in[5];
    float* out = (float*)d_out;

    const int B = out_size;                  // 4
    const int BN = in_sizes[1] / 3;          // B*N
    const int N = BN / B;                    // 2048

    const int tilesPerB = (N + I_TILE - 1) / I_TILE;

    hipMemsetAsync(out, 0, (size_t)out_size * sizeof(float), stream);
    fape_kernel<<<B * tilesPerB, 256, 0, stream>>>(pred_rot, pred_trans, pred_pos,
                                                   true_rot, true_trans, true_pos,
                                                   out, N);
}